// Round 1
// baseline (435.396 us; speedup 1.0000x reference)
//
#include <hip/hip_runtime.h>
#include <hip/hip_bf16.h>

#define HID 64
#define RPW 16
#define KCH 8
#define MROWS 1140   // C(20,3) rows per graph at level 3 (max per-graph rows)

typedef __hip_bfloat16  bf16;
typedef __hip_bfloat162 bf162;
typedef __attribute__((ext_vector_type(8))) short bf8v;
typedef __attribute__((ext_vector_type(4))) float f4v;
__device__ __forceinline__ float bl(bf16 h) { return __bfloat162float(h); }

// -------- FUSED level-1 GNN: one block per graph, 3 layers in LDS.
// Now also emits the level-1 segment sum (comb cols 0..63) — h is already in LDS.
__global__ __launch_bounds__(256)
void level1_k(const float* __restrict__ x,
              const int* __restrict__ rs1, const int* __restrict__ csrc1,
              const float* __restrict__ W10, const float* __restrict__ W20,
              const float* __restrict__ W11, const float* __restrict__ W21,
              const float* __restrict__ W12, const float* __restrict__ W22,
              float* __restrict__ hout, float* __restrict__ comb, int nper) {
    __shared__ float hbuf[20][64];
    __shared__ float mbuf[20][64];
    __shared__ float wl1[64 * 64];
    __shared__ float wl2[64 * 64];
    int g = blockIdx.x, t = threadIdx.x;
    int wv = t >> 6, lane = t & 63;
    int base = g * nper;
    for (int i = t; i < 20 * 32; i += 256)
        hbuf[i >> 5][i & 31] = x[(size_t)(base + (i >> 5)) * 32 + (i & 31)];
    const float* W1s[3] = {W10, W11, W12};
    const float* W2s[3] = {W20, W21, W22};
#pragma unroll 1
    for (int l = 0; l < 3; ++l) {
        int K = (l == 0) ? 32 : 64;
        const float* W1 = W1s[l];
        const float* W2 = W2s[l];
        __syncthreads();
        for (int i = t; i < K * 64; i += 256) {
            int k = i >> 6, col = i & 63;
            wl1[i] = W1[col * K + k];
            wl2[i] = W2[col * K + k];
        }
        __syncthreads();
        float accz[5], accm[5];
#pragma unroll
        for (int ri = 0; ri < 5; ++ri) {
            int r = wv + ri * 4;
            float az = 0.f, am = 0.f;
            for (int k = 0; k < K; ++k) {
                float hv = hbuf[r][k];
                az = fmaf(hv, wl1[k * 64 + lane], az);
                am = fmaf(hv, wl2[k * 64 + lane], am);
            }
            accz[ri] = az; accm[ri] = am;
        }
        __syncthreads();
#pragma unroll
        for (int ri = 0; ri < 5; ++ri)
            mbuf[wv + ri * 4][lane] = accm[ri];
        __syncthreads();
#pragma unroll
        for (int ri = 0; ri < 5; ++ri) {
            int r = wv + ri * 4;
            float acc = accz[ri];
            int s = rs1[base + r], e = rs1[base + r + 1];
            for (int k = s; k < e; ++k)
                acc += mbuf[csrc1[k] - base][lane];
            hbuf[r][lane] = fmaxf(acc, 0.f);
        }
    }
    __syncthreads();
    for (int i = t; i < 20 * 64; i += 256)
        hout[(size_t)(base + (i >> 6)) * 64 + (i & 63)] = hbuf[i >> 6][i & 63];
    if (t < 64) {
        float s = 0.f;
        for (int r = 0; r < nper; ++r) s += hbuf[r][t];
        comb[g * 192 + t] = s;   // level-1 embedding, cols 0..63
    }
}

// -------- batched table GEMM: 5 jobs, bf162 interleaved output.
struct TJob { const float* Wa; const float* Wb; bf162* o; int ldw; int coloff; };
struct TJobs5 { TJob j[5]; };

__global__ __attribute__((amdgpu_flat_work_group_size(256, 256),
                          amdgpu_waves_per_eu(6, 6)))
void gemm2_table(const float* in, TJobs5 jobs, int R, int bpj) {
    int jobi = blockIdx.x / bpj;
    int lb = blockIdx.x % bpj;
    TJob jb = jobs.j[jobi];
    int lane = threadIdx.x & 63;
    int wid = lb * 4 + (threadIdx.x >> 6);
    int j0 = __builtin_amdgcn_readfirstlane(wid * RPW);
    if (j0 >= R) return;
    float accx[RPW], accy[RPW];
#pragma unroll
    for (int r = 0; r < RPW; ++r) { accx[r] = 0.f; accy[r] = 0.f; }
    const float* pa = jb.Wa + (size_t)lane * jb.ldw + jb.coloff;
    const float* pb = jb.Wb + (size_t)lane * jb.ldw + jb.coloff;
#pragma unroll 1
    for (int kc = 0; kc < 64; kc += KCH) {
        float wx[KCH], wy[KCH];
#pragma unroll
        for (int kk = 0; kk < KCH; ++kk) { wx[kk] = pa[kc + kk]; wy[kk] = pb[kc + kk]; }
#pragma unroll
        for (int r = 0; r < RPW; ++r) {
            const float* rp = in + (size_t)(j0 + r) * 64 + kc;
#pragma unroll
            for (int kk = 0; kk < KCH; ++kk) {
                float s = rp[kk];
                accx[r] = fmaf(s, wx[kk], accx[r]);
                accy[r] = fmaf(s, wy[kk], accy[r]);
            }
        }
    }
#pragma unroll
    for (int r = 0; r < RPW; ++r) {
        int j = j0 + r;
        bf162 v; v.x = __float2bfloat16(accx[r]); v.y = __float2bfloat16(accy[r]);
        jb.o[(size_t)j * 64 + lane] = v;
    }
}

// ======== batched CSR build ========
__global__ void zero4_k(int* p1, int s1, int* p2, int s2, int* p3, int s3,
                        int* p4, int s4, int nb1, int nb2, int nb3) {
    int b = blockIdx.x; int* p; int n; int lb;
    if (b < nb1)                 { p = p1; n = s1; lb = b; }
    else if (b < nb1 + nb2)      { p = p2; n = s2; lb = b - nb1; }
    else if (b < nb1 + nb2 + nb3){ p = p3; n = s3; lb = b - nb1 - nb2; }
    else                         { p = p4; n = s4; lb = b - nb1 - nb2 - nb3; }
    int i = lb * 256 + threadIdx.x;
    if (i < n) p[i] = 0;
}

__global__ void hist3_k(const int* e1, int E1, int* c1,
                        const int* e2, int E2, int* c2,
                        const int* e3, int E3, int* c3, int nb1, int nb2) {
    int b = blockIdx.x; const int* dst; int* c; int E; int lb;
    if (b < nb1)            { dst = e1 + E1; c = c1; E = E1; lb = b; }
    else if (b < nb1 + nb2) { dst = e2 + E2; c = c2; E = E2; lb = b - nb1; }
    else                    { dst = e3 + E3; c = c3; E = E3; lb = b - nb1 - nb2; }
    int e = lb * 256 + threadIdx.x;
    if (e < E) atomicAdd(&c[dst[e]], 1);
}

__device__ __forceinline__ void scan1_body(const int* __restrict__ cnt, int* __restrict__ rs,
                                           int* __restrict__ bsum, int n1, int n, int lb) {
    __shared__ int wsum[4];
    int t = threadIdx.x;
    int base = lb * 1024 + t * 4;
    int v[4]; int s = 0;
#pragma unroll
    for (int i = 0; i < 4; ++i) { int idx = base + i; v[i] = s; s += (idx < n) ? cnt[idx] : 0; }
    int lane = t & 63, wv = t >> 6;
    int x = s;
#pragma unroll
    for (int off = 1; off < 64; off <<= 1) { int y = __shfl_up(x, off, 64); if (lane >= off) x += y; }
    if (lane == 63) wsum[wv] = x;
    __syncthreads();
    int woff = 0;
    for (int w = 0; w < wv; ++w) woff += wsum[w];
    int excl = woff + (x - s);
#pragma unroll
    for (int i = 0; i < 4; ++i) { int idx = base + i; if (idx < n1) rs[idx] = excl + v[i]; }
    if (t == 255) bsum[lb] = wsum[0] + wsum[1] + wsum[2] + wsum[3];
}

__global__ void scan1_3k(const int* c1, int* r1, int* b1, int n1a, int na,
                         const int* c2, int* r2, int* b2, int n1b, int nb,
                         const int* c3, int* r3, int* b3, int n1c, int nc,
                         int nbl1, int nbl2) {
    int b = blockIdx.x;
    if (b < nbl1)             scan1_body(c1, r1, b1, n1a, na, b);
    else if (b < nbl1 + nbl2) scan1_body(c2, r2, b2, n1b, nb, b - nbl1);
    else                      scan1_body(c3, r3, b3, n1c, nc, b - nbl1 - nbl2);
}

__device__ __forceinline__ void scan2_body(int* bsum, int nb, int* wsum) {
    int t = threadIdx.x;
    int s = (t < nb) ? bsum[t] : 0;
    int lane = t & 63, wv = t >> 6;
    int x = s;
#pragma unroll
    for (int off = 1; off < 64; off <<= 1) { int y = __shfl_up(x, off, 64); if (lane >= off) x += y; }
    if (lane == 63) wsum[wv] = x;
    __syncthreads();
    int woff = 0;
    for (int w = 0; w < wv; ++w) woff += wsum[w];
    if (t < nb) bsum[t] = woff + x - s;
    __syncthreads();
}

__global__ void scan2_3k(int* b1, int nb1, int* b2, int nb2, int* b3, int nb3) {
    __shared__ int wsum[4];
    scan2_body(b1, nb1, wsum);
    scan2_body(b2, nb2, wsum);
    scan2_body(b3, nb3, wsum);
}

// scan3 + cur-zeroing folded into one dispatch
__global__ void scan3z_k(int* r1, const int* b1, int n1a,
                         int* r2, const int* b2, int n1b,
                         int* r3, const int* b3, int n1c, int nc1, int nc2, int nc3,
                         int* z1, int s1, int* z2, int s2, int* z3, int s3,
                         int nz1, int nz2) {
    int b = blockIdx.x;
    int scanb = nc1 + nc2 + nc3;
    if (b < scanb) {
        int* rs; const int* bsum; int n1; int lb;
        if (b < nc1)            { rs = r1; bsum = b1; n1 = n1a; lb = b; }
        else if (b < nc1 + nc2) { rs = r2; bsum = b2; n1 = n1b; lb = b - nc1; }
        else                    { rs = r3; bsum = b3; n1 = n1c; lb = b - nc1 - nc2; }
        int i = lb * 256 + threadIdx.x;
        if (i < n1) rs[i] += bsum[lb >> 2];
    } else {
        int zb = b - scanb;
        int* p; int n; int lb;
        if (zb < nz1)            { p = z1; n = s1; lb = zb; }
        else if (zb < nz1 + nz2) { p = z2; n = s2; lb = zb - nz1; }
        else                     { p = z3; n = s3; lb = zb - nz1 - nz2; }
        int i = lb * 256 + threadIdx.x;
        if (i < n) p[i] = 0;
    }
}

__global__ void fill3_k(const int* e1, int E1, const int* r1, int* c1, int* s1,
                        const int* e2, int E2, const int* r2, int* c2, int* s2,
                        const int* e3, int E3, const int* r3, int* c3, int* s3,
                        int nb1, int nb2) {
    int b = blockIdx.x;
    const int* edges; int E; const int* rs; int* cur; int* csrc; int lb;
    if (b < nb1)            { edges = e1; E = E1; rs = r1; cur = c1; csrc = s1; lb = b; }
    else if (b < nb1 + nb2) { edges = e2; E = E2; rs = r2; cur = c2; csrc = s2; lb = b - nb1; }
    else                    { edges = e3; E = E3; rs = r3; cur = c3; csrc = s3; lb = b - nb1 - nb2; }
    int e = lb * 256 + threadIdx.x;
    if (e >= E) return;
    int d = edges[E + e];
    int p = rs[d] + atomicAdd(&cur[d], 1);
    csrc[p] = edges[e];
}

// ======== FUSED levels 2+3: one block per (graph, level). ========
// Per graph, the whole layer-0(gather)+neighsum / layer-1(GEMM)+neighsum / segsum
// pipeline runs in one workgroup with the message buffer m resident in LDS
// (1140 rows x 64 bf16 = 142.5 KB < 160 KB). z round-trips through the per-graph
// 142 KB global slice (L1/L2 resident, written+read by the same CU).
struct FJob {
    const bf162 *tA, *tB, *tC;      // precomputed node projections (tC null => level 2)
    const int *ga, *gb, *gc;        // global node ids per row
    const float* iso;               // level3: float4 per row; level2: float per row
    const float *wc1, *wc2;         // W_0 iso-column block (per out-feature f: [f*ldw + c])
    int ldw, isoC;
    const float *Wl1, *Wl2;         // layer-1 weights, row-major [64][64]
    const int *rs; const int *csrc; // CSR over destination rows (global row ids)
    bf16 *zb, *zc;                  // per-row z buffers (bf16 [n][64])
    int P;                          // rows per graph (1140 / 190)
    int comboff;                    // 128 / 64
};

// neighsum over LDS-resident m. f2 = lane&31 covers the 32 bf162 feature pairs;
// bank = f2 -> 2 lanes/bank across the wave = free (m136).
template <bool WRITE>
__device__ __forceinline__ void neigh_phase(const FJob& jb, int g, int t,
                                            const bf16* mL, const bf16* zin, bf16* zout,
                                            float& sx, float& sy) {
    int f2 = t & 31, grp = t >> 5;
    const bf162* mi = (const bf162*)mL;
    const bf162* zi = (const bf162*)zin;
    bf162* zo = (bf162*)zout;
    int gbase = g * jb.P;
    for (int row = grp; row < jb.P; row += 32) {
        size_t gr = (size_t)gbase + row;
        int s = jb.rs[gr], e = jb.rs[gr + 1];
        bf162 z0 = zi[gr * 32 + f2];
        float ax = bl(z0.x), ay = bl(z0.y);
        int k = s;
        for (; k + 4 <= e; k += 4) {
            int i0 = jb.csrc[k] - gbase,     i1 = jb.csrc[k + 1] - gbase;
            int i2 = jb.csrc[k + 2] - gbase, i3 = jb.csrc[k + 3] - gbase;
            bf162 v0 = mi[i0 * 32 + f2], v1 = mi[i1 * 32 + f2];
            bf162 v2 = mi[i2 * 32 + f2], v3 = mi[i3 * 32 + f2];
            ax += (bl(v0.x) + bl(v1.x)) + (bl(v2.x) + bl(v3.x));
            ay += (bl(v0.y) + bl(v1.y)) + (bl(v2.y) + bl(v3.y));
        }
        for (; k < e; ++k) {
            int i0 = jb.csrc[k] - gbase;
            bf162 v = mi[i0 * 32 + f2];
            ax += bl(v.x); ay += bl(v.y);
        }
        ax = fmaxf(ax, 0.f); ay = fmaxf(ay, 0.f);
        if (WRITE) {
            bf162 o; o.x = __float2bfloat16(ax); o.y = __float2bfloat16(ay);
            zo[gr * 32 + f2] = o;
        } else { sx += ax; sy += ay; }
    }
}

__global__ __launch_bounds__(1024, 1)
void fused23_k(FJob j3, FJob j2, float* __restrict__ comb, int G) {
    // 145920 + 16384 = 162304 B <= 163840 B (gfx950 LDS cap); 1 block/CU.
    __shared__ __align__(16) bf16 mLDS[MROWS * HID];
    __shared__ __align__(16) bf16 wstage[8192];   // phase0/1: hs tables; phase3: W frags; phase4: f32 partials
    int t = threadIdx.x;
    int g; FJob jb;
    if ((int)blockIdx.x < G) { jb = j3; g = blockIdx.x; }
    else                     { jb = j2; g = blockIdx.x - G; }
    const int P = jb.P;
    const int nT = jb.tC ? 3 : 2;

    // ---- phase 0: stage projected node tables (contiguous 1280-bf162 slices/graph)
    bf162* hs = (bf162*)wstage;
    for (int i = t; i < nT * 1280; i += 1024) {
        int which = i / 1280, rem = i - which * 1280;
        const bf162* src = (which == 0) ? jb.tA : (which == 1) ? jb.tB : jb.tC;
        hs[i] = src[(size_t)g * 1280 + rem];
    }
    int f = t & 63;
    float w1c[4], w2c[4];
#pragma unroll
    for (int c = 0; c < 4; ++c) {
        w1c[c] = (c < jb.isoC) ? jb.wc1[f * jb.ldw + c] : 0.f;
        w2c[c] = (c < jb.isoC) ? jb.wc2[f * jb.ldw + c] : 0.f;
    }
    __syncthreads();

    // ---- phase 1: layer-0 gather -> z (global, bf16) + m (LDS)
    {
        const bf162* hA = hs; const bf162* hB = hs + 1280; const bf162* hC = hs + 2560;
        int gbase = g * P;
        for (int row = t >> 6; row < P; row += 16) {
            size_t gr = (size_t)gbase + row;
            float zz, mm;
            if (nT == 3) {
                int a = jb.ga[gr] - g * 20, b = jb.gb[gr] - g * 20, c = jb.gc[gr] - g * 20;
                float4 iv = ((const float4*)jb.iso)[gr];
                bf162 va = hA[a * 64 + f], vb = hB[b * 64 + f], vc = hC[c * 64 + f];
                zz = bl(va.x) + bl(vb.x) + bl(vc.x)
                   + iv.x * w1c[0] + iv.y * w1c[1] + iv.z * w1c[2] + iv.w * w1c[3];
                mm = bl(va.y) + bl(vb.y) + bl(vc.y)
                   + iv.x * w2c[0] + iv.y * w2c[1] + iv.z * w2c[2] + iv.w * w2c[3];
            } else {
                int u = jb.ga[gr] - g * 20, v = jb.gb[gr] - g * 20;
                float is = jb.iso[gr];
                bf162 vu = hA[u * 64 + f], vv = hB[v * 64 + f];
                zz = bl(vu.x) + bl(vv.x) + is * w1c[0];
                mm = bl(vu.y) + bl(vv.y) + is * w2c[0];
            }
            mLDS[row * HID + f] = __float2bfloat16(mm);
            jb.zb[gr * HID + f] = __float2bfloat16(zz);
        }
    }
    __syncthreads();

    // ---- phase 2 (+3a): stage layer-1 W frags (hs no longer needed), neighsum-1 in place.
    // Frag-major W layout: idx = ((((n*2+mat)*2+kt)*4+quad)*16+m16)*8+e -> each wave's
    // 64 b128 B-frag lanes read 1024 contiguous bytes = conflict-free.
    for (int i = t; i < 8192; i += 1024) {
        int e = i & 7, m16 = (i >> 3) & 15, quad = (i >> 7) & 3;
        int kt = (i >> 9) & 1, mat = (i >> 10) & 1, n = i >> 11;
        const float* W = mat ? jb.Wl2 : jb.Wl1;
        wstage[i] = __float2bfloat16(W[(n * 16 + m16) * HID + kt * 32 + quad * 8 + e]);
    }
    {
        float dx = 0.f, dy = 0.f;
        neigh_phase<true>(jb, g, t, mLDS, jb.zb, jb.zb, dx, dy);
    }
    __syncthreads();

    // ---- phase 3b: dual MFMA GEMM  zc = zb @ Wl1^T (global), m1 = zb @ Wl2^T (LDS)
    {
        int lane = t & 63, wv = t >> 6;
        int quad = lane >> 4, m16 = lane & 15;
        int gbase = g * P;
        int ntiles = (P + 31) >> 5;
        for (int tile = wv; tile < ntiles; tile += 16) {
            int j0 = tile * 32;
            bf8v a[2][2];
#pragma unroll
            for (int rt = 0; rt < 2; ++rt) {
                int row = j0 + rt * 16 + m16;
#pragma unroll
                for (int kt = 0; kt < 2; ++kt) {
                    bf8v v = {0, 0, 0, 0, 0, 0, 0, 0};
                    if (row < P)
                        v = *(const bf8v*)(jb.zb + ((size_t)gbase + row) * HID + kt * 32 + quad * 8);
                    a[rt][kt] = v;
                }
            }
#pragma unroll
            for (int n = 0; n < 4; ++n) {
                const bf8v b1k0 = *(const bf8v*)(wstage + ((((n * 2 + 0) * 2 + 0) * 4 + quad) * 16 + m16) * 8);
                const bf8v b1k1 = *(const bf8v*)(wstage + ((((n * 2 + 0) * 2 + 1) * 4 + quad) * 16 + m16) * 8);
                const bf8v b2k0 = *(const bf8v*)(wstage + ((((n * 2 + 1) * 2 + 0) * 4 + quad) * 16 + m16) * 8);
                const bf8v b2k1 = *(const bf8v*)(wstage + ((((n * 2 + 1) * 2 + 1) * 4 + quad) * 16 + m16) * 8);
#pragma unroll
                for (int rt = 0; rt < 2; ++rt) {
                    f4v acca = {0.f, 0.f, 0.f, 0.f};
                    f4v accb = {0.f, 0.f, 0.f, 0.f};
                    acca = __builtin_amdgcn_mfma_f32_16x16x32_bf16(a[rt][0], b1k0, acca, 0, 0, 0);
                    acca = __builtin_amdgcn_mfma_f32_16x16x32_bf16(a[rt][1], b1k1, acca, 0, 0, 0);
                    accb = __builtin_amdgcn_mfma_f32_16x16x32_bf16(a[rt][0], b2k0, accb, 0, 0, 0);
                    accb = __builtin_amdgcn_mfma_f32_16x16x32_bf16(a[rt][1], b2k1, accb, 0, 0, 0);
                    int col = n * 16 + m16;
#pragma unroll
                    for (int r = 0; r < 4; ++r) {
                        int row = j0 + rt * 16 + quad * 4 + r;
                        if (row < P) {
                            jb.zc[((size_t)gbase + row) * HID + col] = __float2bfloat16(acca[r]);
                            mLDS[row * HID + col] = __float2bfloat16(accb[r]);
                        }
                    }
                }
            }
        }
    }
    __syncthreads();

    // ---- phase 4: neighsum-2 + per-graph segment sum (no global z3 write needed)
    float sx = 0.f, sy = 0.f;
    neigh_phase<false>(jb, g, t, mLDS, jb.zc, nullptr, sx, sy);
    float* part = (float*)wstage;    // [32 grp][64 features]
    int f2 = t & 31, grp = t >> 5;
    part[grp * 64 + f2 * 2]     = sx;
    part[grp * 64 + f2 * 2 + 1] = sy;
    __syncthreads();
    if (t < 64) {
        float s = 0.f;
        for (int gg = 0; gg < 32; ++gg) s += part[gg * 64 + t];
        comb[g * 192 + jb.comboff + t] = s;
    }
}

// -------- classifier
__global__ void classifier_k(const float* __restrict__ comb,
                             const float* __restrict__ cW1, const float* __restrict__ cb1,
                             const float* __restrict__ cW2, const float* __restrict__ cb2,
                             float* __restrict__ out) {
    __shared__ float row[192];
    __shared__ float hid[64];
    int g = blockIdx.x, t = threadIdx.x;
    for (int i = t; i < 192; i += 64) row[i] = comb[g * 192 + i];
    __syncthreads();
    float acc = cb1[t];
#pragma unroll 8
    for (int k = 0; k < 192; ++k) acc += row[k] * cW1[t * 192 + k];
    hid[t] = fmaxf(acc, 0.f);
    __syncthreads();
    if (t < 10) {
        float o = cb2[t];
#pragma unroll
        for (int k = 0; k < 64; ++k) o += hid[k] * cW2[t * 64 + k];
        out[g * 10 + t] = o;
    }
}

static inline int cdiv(long long a, long long b) { return (int)((a + b - 1) / b); }

extern "C" void kernel_launch(void* const* d_in, const int* in_sizes, int n_in,
                              void* d_out, int out_size, void* d_ws, size_t ws_size,
                              hipStream_t stream) {
    const float* x        = (const float*)d_in[0];
    const int*   eidx     = (const int*)d_in[1];
    const int*   gu2      = (const int*)d_in[3];
    const int*   gv2      = (const int*)d_in[4];
    const float* iso2     = (const float*)d_in[5];
    const int*   tedges   = (const int*)d_in[6];
    const int*   ga3      = (const int*)d_in[8];
    const int*   gb3      = (const int*)d_in[9];
    const int*   gc3      = (const int*)d_in[10];
    const float* iso3     = (const float*)d_in[11];
    const int*   hedges   = (const int*)d_in[12];
    const float* g1W1[3]  = {(const float*)d_in[14], (const float*)d_in[16], (const float*)d_in[18]};
    const float* g1W2[3]  = {(const float*)d_in[15], (const float*)d_in[17], (const float*)d_in[19]};
    const float* g2W1_0   = (const float*)d_in[20];
    const float* g2W2_0   = (const float*)d_in[21];
    const float* g2W1_1   = (const float*)d_in[22];
    const float* g2W2_1   = (const float*)d_in[23];
    const float* g3W1_0   = (const float*)d_in[24];
    const float* g3W2_0   = (const float*)d_in[25];
    const float* g3W1_1   = (const float*)d_in[26];
    const float* g3W2_1   = (const float*)d_in[27];
    const float* cW1      = (const float*)d_in[28];
    const float* cb1      = (const float*)d_in[29];
    const float* cW2      = (const float*)d_in[30];
    const float* cb2      = (const float*)d_in[31];
    float* out = (float*)d_out;

    const int N  = in_sizes[0] / 32;       // 2560
    const int E1 = in_sizes[1] / 2;
    const int n2 = in_sizes[3];            // 24320
    const int E2 = in_sizes[6] / 2;
    const int n3 = in_sizes[8];            // 145920
    const int E3 = in_sizes[12] / 2;
    const int G  = out_size / 10;          // 128
    const int per1 = N / G, per2 = n2 / G, per3 = n3 / G;

    // ---- workspace carve-up
    float* ws = (float*)d_ws;
    size_t off = 0;
    auto alloc = [&](size_t n) { off = (off + 3) & ~(size_t)3; float* p = ws + off; off += n; return p; };
    const size_t NH = (size_t)N * HID;
    float* h0 = alloc(NH);
    bf162* hUi = (bf162*)alloc(NH); bf162* hVi = (bf162*)alloc(NH);
    bf162* hAi = (bf162*)alloc(NH); bf162* hBi = (bf162*)alloc(NH); bf162* hCi = (bf162*)alloc(NH);
    bf16* z2b = (bf16*)alloc((size_t)n2 * HID / 2 + 64);
    bf16* z2c = (bf16*)alloc((size_t)n2 * HID / 2 + 64);
    bf16* z3b = (bf16*)alloc((size_t)n3 * HID / 2 + 64);
    bf16* z3c = (bf16*)alloc((size_t)n3 * HID / 2 + 64);
    float* comb = alloc((size_t)G * 192);
    int* iws = (int*)(ws + off);
    size_t ioff = 0;
    auto ialloc = [&](size_t n) { int* p = iws + ioff; ioff += n; return p; };
    int* rs1 = ialloc(N + 1);  int* cur1 = ialloc(N);  int* csrc1 = ialloc(E1);
    int* rs2 = ialloc(n2 + 1); int* cur2 = ialloc(n2); int* csrc2 = ialloc(E2);
    int* rs3 = ialloc(n3 + 1); int* cur3 = ialloc(n3); int* csrc3 = ialloc(E3);
    int* bsum1 = ialloc(256); int* bsum2 = ialloc(256); int* bsum3 = ialloc(256);
    (void)ws_size;

    dim3 B256(256);

    // ---- batched CSR build (6 dispatches; cur re-zero folded into scan3z)
    int nz1 = cdiv(N, 256), nz2 = cdiv(n2, 256), nz3 = cdiv(n3, 256);
    zero4_k<<<nz1 + nz2 + nz3, B256, 0, stream>>>(
        cur1, N, cur2, n2, cur3, n3, cur3, 0, nz1, nz2, nz3);
    int ne1 = cdiv(E1, 256), ne2 = cdiv(E2, 256), ne3 = cdiv(E3, 256);
    hist3_k<<<ne1 + ne2 + ne3, B256, 0, stream>>>(
        eidx, E1, cur1, tedges, E2, cur2, hedges, E3, cur3, ne1, ne2);
    int ns1 = cdiv(N + 1, 1024), ns2 = cdiv(n2 + 1, 1024), ns3 = cdiv(n3 + 1, 1024);
    scan1_3k<<<ns1 + ns2 + ns3, B256, 0, stream>>>(
        cur1, rs1, bsum1, N + 1, N, cur2, rs2, bsum2, n2 + 1, n2,
        cur3, rs3, bsum3, n3 + 1, n3, ns1, ns2);
    scan2_3k<<<1, B256, 0, stream>>>(bsum1, ns1, bsum2, ns2, bsum3, ns3);
    int nc1 = cdiv(N + 1, 256), nc2 = cdiv(n2 + 1, 256), nc3 = cdiv(n3 + 1, 256);
    scan3z_k<<<nc1 + nc2 + nc3 + nz1 + nz2 + nz3, B256, 0, stream>>>(
        rs1, bsum1, N + 1, rs2, bsum2, n2 + 1, rs3, bsum3, n3 + 1, nc1, nc2, nc3,
        cur1, N, cur2, n2, cur3, n3, nz1, nz2);
    fill3_k<<<ne1 + ne2 + ne3, B256, 0, stream>>>(
        eidx, E1, rs1, cur1, csrc1, tedges, E2, rs2, cur2, csrc2,
        hedges, E3, rs3, cur3, csrc3, ne1, ne2);

    // ================= level 1: FUSED single kernel (+ its segment sum) =================
    level1_k<<<G, B256, 0, stream>>>(x, rs1, csrc1,
        g1W1[0], g1W2[0], g1W1[1], g1W2[1], g1W1[2], g1W2[2], h0, comb, per1);
    const float* h = h0;

    // ---- all 5 table GEMMs in ONE dispatch
    {
        TJobs5 jobs;
        jobs.j[0] = {g2W1_0, g2W2_0, hUi, 129, 0};
        jobs.j[1] = {g2W1_0, g2W2_0, hVi, 129, 64};
        jobs.j[2] = {g3W1_0, g3W2_0, hAi, 196, 0};
        jobs.j[3] = {g3W1_0, g3W2_0, hBi, 196, 64};
        jobs.j[4] = {g3W1_0, g3W2_0, hCi, 196, 128};
        int bpj = cdiv(cdiv(N, RPW), 4);
        gemm2_table<<<bpj * 5, B256, 0, stream>>>(h, jobs, N, bpj);
    }

    // ================= levels 2+3: single fused per-graph kernel =================
    {
        FJob j3, j2;
        j3.tA = hAi; j3.tB = hBi; j3.tC = hCi;
        j3.ga = ga3; j3.gb = gb3; j3.gc = gc3;
        j3.iso = iso3; j3.wc1 = g3W1_0 + 192; j3.wc2 = g3W2_0 + 192; j3.ldw = 196; j3.isoC = 4;
        j3.Wl1 = g3W1_1; j3.Wl2 = g3W2_1; j3.rs = rs3; j3.csrc = csrc3;
        j3.zb = z3b; j3.zc = z3c; j3.P = per3; j3.comboff = 128;
        j2.tA = hUi; j2.tB = hVi; j2.tC = nullptr;
        j2.ga = gu2; j2.gb = gv2; j2.gc = nullptr;
        j2.iso = iso2; j2.wc1 = g2W1_0 + 128; j2.wc2 = g2W2_0 + 128; j2.ldw = 129; j2.isoC = 1;
        j2.Wl1 = g2W1_1; j2.Wl2 = g2W2_1; j2.rs = rs2; j2.csrc = csrc2;
        j2.zb = z2b; j2.zc = z2c; j2.P = per2; j2.comboff = 64;
        fused23_k<<<2 * G, 1024, 0, stream>>>(j3, j2, comb, G);
    }

    // ================= classifier =================
    classifier_k<<<G, 64, 0, stream>>>(comb, cW1, cb1, cW2, cb2, out);
}

// Round 2
// 326.950 us; speedup vs baseline: 1.3317x; 1.3317x over previous
//
#include <hip/hip_runtime.h>
#include <hip/hip_bf16.h>

#define HID 64
#define RPW 16
#define KCH 8
#define MROWS 1140   // C(20,3) rows per graph at level 3 (max per-graph rows)

typedef __hip_bfloat16  bf16;
typedef __hip_bfloat162 bf162;
typedef __attribute__((ext_vector_type(8))) short bf8v;
typedef __attribute__((ext_vector_type(4))) float f4v;
typedef __attribute__((ext_vector_type(4))) unsigned int u4v;
__device__ __forceinline__ float bl(bf16 h) { return __bfloat162float(h); }

// -------- FUSED level-1 GNN: one block per graph, 3 layers in LDS.
// Also emits the level-1 segment sum (comb cols 0..63) — h is already in LDS.
__global__ __launch_bounds__(256)
void level1_k(const float* __restrict__ x,
              const int* __restrict__ rs1, const int* __restrict__ csrc1,
              const float* __restrict__ W10, const float* __restrict__ W20,
              const float* __restrict__ W11, const float* __restrict__ W21,
              const float* __restrict__ W12, const float* __restrict__ W22,
              float* __restrict__ hout, float* __restrict__ comb, int nper) {
    __shared__ float hbuf[20][64];
    __shared__ float mbuf[20][64];
    __shared__ float wl1[64 * 64];
    __shared__ float wl2[64 * 64];
    int g = blockIdx.x, t = threadIdx.x;
    int wv = t >> 6, lane = t & 63;
    int base = g * nper;
    for (int i = t; i < 20 * 32; i += 256)
        hbuf[i >> 5][i & 31] = x[(size_t)(base + (i >> 5)) * 32 + (i & 31)];
    const float* W1s[3] = {W10, W11, W12};
    const float* W2s[3] = {W20, W21, W22};
#pragma unroll 1
    for (int l = 0; l < 3; ++l) {
        int K = (l == 0) ? 32 : 64;
        const float* W1 = W1s[l];
        const float* W2 = W2s[l];
        __syncthreads();
        for (int i = t; i < K * 64; i += 256) {
            int k = i >> 6, col = i & 63;
            wl1[i] = W1[col * K + k];
            wl2[i] = W2[col * K + k];
        }
        __syncthreads();
        float accz[5], accm[5];
#pragma unroll
        for (int ri = 0; ri < 5; ++ri) {
            int r = wv + ri * 4;
            float az = 0.f, am = 0.f;
            for (int k = 0; k < K; ++k) {
                float hv = hbuf[r][k];
                az = fmaf(hv, wl1[k * 64 + lane], az);
                am = fmaf(hv, wl2[k * 64 + lane], am);
            }
            accz[ri] = az; accm[ri] = am;
        }
        __syncthreads();
#pragma unroll
        for (int ri = 0; ri < 5; ++ri)
            mbuf[wv + ri * 4][lane] = accm[ri];
        __syncthreads();
#pragma unroll
        for (int ri = 0; ri < 5; ++ri) {
            int r = wv + ri * 4;
            float acc = accz[ri];
            int s = rs1[base + r], e = rs1[base + r + 1];
            for (int k = s; k < e; ++k)
                acc += mbuf[csrc1[k] - base][lane];
            hbuf[r][lane] = fmaxf(acc, 0.f);
        }
    }
    __syncthreads();
    for (int i = t; i < 20 * 64; i += 256)
        hout[(size_t)(base + (i >> 6)) * 64 + (i & 63)] = hbuf[i >> 6][i & 63];
    if (t < 64) {
        float s = 0.f;
        for (int r = 0; r < nper; ++r) s += hbuf[r][t];
        comb[g * 192 + t] = s;   // level-1 embedding, cols 0..63
    }
}

// -------- batched table GEMM: 5 jobs, bf162 interleaved output.
struct TJob { const float* Wa; const float* Wb; bf162* o; int ldw; int coloff; };
struct TJobs5 { TJob j[5]; };

__global__ __attribute__((amdgpu_flat_work_group_size(256, 256),
                          amdgpu_waves_per_eu(6, 6)))
void gemm2_table(const float* in, TJobs5 jobs, int R, int bpj) {
    int jobi = blockIdx.x / bpj;
    int lb = blockIdx.x % bpj;
    TJob jb = jobs.j[jobi];
    int lane = threadIdx.x & 63;
    int wid = lb * 4 + (threadIdx.x >> 6);
    int j0 = __builtin_amdgcn_readfirstlane(wid * RPW);
    if (j0 >= R) return;
    float accx[RPW], accy[RPW];
#pragma unroll
    for (int r = 0; r < RPW; ++r) { accx[r] = 0.f; accy[r] = 0.f; }
    const float* pa = jb.Wa + (size_t)lane * jb.ldw + jb.coloff;
    const float* pb = jb.Wb + (size_t)lane * jb.ldw + jb.coloff;
#pragma unroll 1
    for (int kc = 0; kc < 64; kc += KCH) {
        float wx[KCH], wy[KCH];
#pragma unroll
        for (int kk = 0; kk < KCH; ++kk) { wx[kk] = pa[kc + kk]; wy[kk] = pb[kc + kk]; }
#pragma unroll
        for (int r = 0; r < RPW; ++r) {
            const float* rp = in + (size_t)(j0 + r) * 64 + kc;
#pragma unroll
            for (int kk = 0; kk < KCH; ++kk) {
                float s = rp[kk];
                accx[r] = fmaf(s, wx[kk], accx[r]);
                accy[r] = fmaf(s, wy[kk], accy[r]);
            }
        }
    }
#pragma unroll
    for (int r = 0; r < RPW; ++r) {
        int j = j0 + r;
        bf162 v; v.x = __float2bfloat16(accx[r]); v.y = __float2bfloat16(accy[r]);
        jb.o[(size_t)j * 64 + lane] = v;
    }
}

// ======== batched CSR build ========
__global__ void zero4_k(int* p1, int s1, int* p2, int s2, int* p3, int s3,
                        int* p4, int s4, int nb1, int nb2, int nb3) {
    int b = blockIdx.x; int* p; int n; int lb;
    if (b < nb1)                 { p = p1; n = s1; lb = b; }
    else if (b < nb1 + nb2)      { p = p2; n = s2; lb = b - nb1; }
    else if (b < nb1 + nb2 + nb3){ p = p3; n = s3; lb = b - nb1 - nb2; }
    else                         { p = p4; n = s4; lb = b - nb1 - nb2 - nb3; }
    int i = lb * 256 + threadIdx.x;
    if (i < n) p[i] = 0;
}

__global__ void hist3_k(const int* e1, int E1, int* c1,
                        const int* e2, int E2, int* c2,
                        const int* e3, int E3, int* c3, int nb1, int nb2) {
    int b = blockIdx.x; const int* dst; int* c; int E; int lb;
    if (b < nb1)            { dst = e1 + E1; c = c1; E = E1; lb = b; }
    else if (b < nb1 + nb2) { dst = e2 + E2; c = c2; E = E2; lb = b - nb1; }
    else                    { dst = e3 + E3; c = c3; E = E3; lb = b - nb1 - nb2; }
    int e = lb * 256 + threadIdx.x;
    if (e < E) atomicAdd(&c[dst[e]], 1);
}

__device__ __forceinline__ void scan1_body(const int* __restrict__ cnt, int* __restrict__ rs,
                                           int* __restrict__ bsum, int n1, int n, int lb) {
    __shared__ int wsum[4];
    int t = threadIdx.x;
    int base = lb * 1024 + t * 4;
    int v[4]; int s = 0;
#pragma unroll
    for (int i = 0; i < 4; ++i) { int idx = base + i; v[i] = s; s += (idx < n) ? cnt[idx] : 0; }
    int lane = t & 63, wv = t >> 6;
    int x = s;
#pragma unroll
    for (int off = 1; off < 64; off <<= 1) { int y = __shfl_up(x, off, 64); if (lane >= off) x += y; }
    if (lane == 63) wsum[wv] = x;
    __syncthreads();
    int woff = 0;
    for (int w = 0; w < wv; ++w) woff += wsum[w];
    int excl = woff + (x - s);
#pragma unroll
    for (int i = 0; i < 4; ++i) { int idx = base + i; if (idx < n1) rs[idx] = excl + v[i]; }
    if (t == 255) bsum[lb] = wsum[0] + wsum[1] + wsum[2] + wsum[3];
}

__global__ void scan1_3k(const int* c1, int* r1, int* b1, int n1a, int na,
                         const int* c2, int* r2, int* b2, int n1b, int nb,
                         const int* c3, int* r3, int* b3, int n1c, int nc,
                         int nbl1, int nbl2) {
    int b = blockIdx.x;
    if (b < nbl1)             scan1_body(c1, r1, b1, n1a, na, b);
    else if (b < nbl1 + nbl2) scan1_body(c2, r2, b2, n1b, nb, b - nbl1);
    else                      scan1_body(c3, r3, b3, n1c, nc, b - nbl1 - nbl2);
}

__device__ __forceinline__ void scan2_body(int* bsum, int nb, int* wsum) {
    int t = threadIdx.x;
    int s = (t < nb) ? bsum[t] : 0;
    int lane = t & 63, wv = t >> 6;
    int x = s;
#pragma unroll
    for (int off = 1; off < 64; off <<= 1) { int y = __shfl_up(x, off, 64); if (lane >= off) x += y; }
    if (lane == 63) wsum[wv] = x;
    __syncthreads();
    int woff = 0;
    for (int w = 0; w < wv; ++w) woff += wsum[w];
    if (t < nb) bsum[t] = woff + x - s;
    __syncthreads();
}

__global__ void scan2_3k(int* b1, int nb1, int* b2, int nb2, int* b3, int nb3) {
    __shared__ int wsum[4];
    scan2_body(b1, nb1, wsum);
    scan2_body(b2, nb2, wsum);
    scan2_body(b3, nb3, wsum);
}

// scan3 + cur-zeroing folded into one dispatch
__global__ void scan3z_k(int* r1, const int* b1, int n1a,
                         int* r2, const int* b2, int n1b,
                         int* r3, const int* b3, int n1c, int nc1, int nc2, int nc3,
                         int* z1, int s1, int* z2, int s2, int* z3, int s3,
                         int nz1, int nz2) {
    int b = blockIdx.x;
    int scanb = nc1 + nc2 + nc3;
    if (b < scanb) {
        int* rs; const int* bsum; int n1; int lb;
        if (b < nc1)            { rs = r1; bsum = b1; n1 = n1a; lb = b; }
        else if (b < nc1 + nc2) { rs = r2; bsum = b2; n1 = n1b; lb = b - nc1; }
        else                    { rs = r3; bsum = b3; n1 = n1c; lb = b - nc1 - nc2; }
        int i = lb * 256 + threadIdx.x;
        if (i < n1) rs[i] += bsum[lb >> 2];
    } else {
        int zb = b - scanb;
        int* p; int n; int lb;
        if (zb < nz1)            { p = z1; n = s1; lb = zb; }
        else if (zb < nz1 + nz2) { p = z2; n = s2; lb = zb - nz1; }
        else                     { p = z3; n = s3; lb = zb - nz1 - nz2; }
        int i = lb * 256 + threadIdx.x;
        if (i < n) p[i] = 0;
    }
}

__global__ void fill3_k(const int* e1, int E1, const int* r1, int* c1, int* s1,
                        const int* e2, int E2, const int* r2, int* c2, int* s2,
                        const int* e3, int E3, const int* r3, int* c3, int* s3,
                        int nb1, int nb2) {
    int b = blockIdx.x;
    const int* edges; int E; const int* rs; int* cur; int* csrc; int lb;
    if (b < nb1)            { edges = e1; E = E1; rs = r1; cur = c1; csrc = s1; lb = b; }
    else if (b < nb1 + nb2) { edges = e2; E = E2; rs = r2; cur = c2; csrc = s2; lb = b - nb1; }
    else                    { edges = e3; E = E3; rs = r3; cur = c3; csrc = s3; lb = b - nb1 - nb2; }
    int e = lb * 256 + threadIdx.x;
    if (e >= E) return;
    int d = edges[E + e];
    int p = rs[d] + atomicAdd(&cur[d], 1);
    csrc[p] = edges[e];
}

// ======== FUSED levels 2+3 v2: one block per (graph, level), A-frag ownership. ========
// Thread (quad=lane>>4, m16=lane&15) owns rows tile*32+rt*16+m16, feats kt*32+quad*8..+7
// == the MFMA A-fragment layout. z / zb live in REGISTERS across phases (no global zb).
// m lives in LDS (XOR-swizzled chunks: chunk ^= row&7 -> conflict-free b128). Only zc
// (layer-1 preact) round-trips global (D-layout != A-layout). 256 rows in flight / CU.
struct FJob {
    const bf162 *tA, *tB, *tC;      // projected node tables (tC null => level 2)
    const int *ga, *gb, *gc;        // global node ids per row
    const float* iso;               // level3: float4 one-hot per row; level2: float per row
    const float *wc1, *wc2;         // W_0 iso-column block base (jb.wcX[f*ldw + c])
    int ldw, isoC;
    const float *Wl1, *Wl2;         // layer-1 weights, row-major [64][64]
    const int *rs; const int *csrc; // CSR over destination rows (global row ids)
    bf16 *zc;                       // layer-1 preact scratch (bf16 [n][64])
    int P;                          // rows per graph (1140 / 190)
    int comboff;                    // 128 / 64
};

__device__ __forceinline__ int msw(int row, int ch) {    // bf16 index of swizzled chunk
    return (row << 6) + ((ch ^ (row & 7)) << 3);
}
__device__ __forceinline__ void accu4(u4v v, float* f) { // bf16x8 += into f[0..7]
#pragma unroll
    for (int i = 0; i < 4; ++i) {
        f[2 * i]     += __uint_as_float(v[i] << 16);
        f[2 * i + 1] += __uint_as_float(v[i] & 0xffff0000u);
    }
}
__device__ __forceinline__ void accxy4(u4v v, float* zx, float* zy) { // bf162x4 split-acc
#pragma unroll
    for (int i = 0; i < 4; ++i) {
        zx[i] += __uint_as_float(v[i] << 16);
        zy[i] += __uint_as_float(v[i] & 0xffff0000u);
    }
}
__device__ __forceinline__ bf8v pack8(const float* f) {
    bf16 tmp[8];
#pragma unroll
    for (int e = 0; e < 8; ++e) tmp[e] = __float2bfloat16(f[e]);
    bf8v r; __builtin_memcpy(&r, tmp, 16); return r;
}
__device__ __forceinline__ bf8v pack8relu(const float* f) {
    bf16 tmp[8];
#pragma unroll
    for (int e = 0; e < 8; ++e) tmp[e] = __float2bfloat16(fmaxf(f[e], 0.f));
    bf8v r; __builtin_memcpy(&r, tmp, 16); return r;
}
__device__ __forceinline__ u4v asu4(bf8v v) { u4v r; __builtin_memcpy(&r, &v, 16); return r; }
// hs tables: bf162[node][64] with chunk-of-4 swizzle: pos = node*64 + ((c4^(node&15))<<2)+(f&3)
__device__ __forceinline__ void hsacc(const bf162* tb, int nd, int c4, float* zx, float* zy) {
    u4v v0 = *(const u4v*)(tb + (nd << 6) + (((c4    ) ^ (nd & 15)) << 2));
    u4v v1 = *(const u4v*)(tb + (nd << 6) + (((c4 + 1) ^ (nd & 15)) << 2));
    accxy4(v0, zx, zy);
    accxy4(v1, zx + 4, zy + 4);
}
__device__ __forceinline__ void naccum(const bf16* mL, int nbr, int quad, float* acc) {
    u4v v0 = *(const u4v*)(mL + msw(nbr, quad));
    u4v v1 = *(const u4v*)(mL + msw(nbr, quad + 4));
    accu4(v0, acc); accu4(v1, acc + 8);
}

__global__ __launch_bounds__(1024, 1)
void fused23_k(FJob j3, FJob j2, float* __restrict__ comb, int G) {
    // 145920 (m) + 17536 (stage union) = 163456 B <= 163840 B; 1 block/CU, 16 waves.
    __shared__ __align__(16) bf16 mLDS[MROWS * HID];
    __shared__ __align__(16) bf16 wstage[8768];
    int t = threadIdx.x;
    int g; FJob jb;
    if ((int)blockIdx.x < G) { jb = j3; g = blockIdx.x; }
    else                     { jb = j2; g = blockIdx.x - G; }
    const int P = jb.P;
    const int nT = jb.tC ? 3 : 2;
    const int ntiles = (P + 31) >> 5;
    const int gbase = g * P, nb20 = g * 20;
    int lane = t & 63, wv = t >> 6, quad = lane >> 4, m16 = lane & 15;

    // ---- P0: stage projected node tables (swizzled) + iso-weight table
    bf162* hsA = (bf162*)wstage;
    const bf162* hsB = hsA + 1280;
    const bf162* hsC = hsA + 2560;
    for (int i = t; i < nT * 1280; i += 1024) {
        int table = i / 1280, rem = i - table * 1280;
        int node = rem >> 6, f = rem & 63, c4 = f >> 2;
        const bf162* src = (table == 0) ? jb.tA : (table == 1) ? jb.tB : jb.tC;
        hsA[table * 1280 + (node << 6) + ((c4 ^ (node & 15)) << 2) + (f & 3)] =
            src[(size_t)g * 1280 + rem];
    }
    float* wcT = (float*)(wstage + 7680);   // [2 mats][4 c][64 f]
    if (t < 512) {
        int mat = t >> 8, c = (t >> 6) & 3, f = t & 63;
        const float* W = mat ? jb.wc2 : jb.wc1;
        wcT[mat * 256 + c * 64 + f] = (c < jb.isoC) ? W[f * jb.ldw + c] : 0.f;
    }
    __syncthreads();

    // ---- P1: layer-0 gather -> z (regs, A-frag layout) + m0 (LDS, swizzled)
    bf8v z8[3][2][2];
#pragma unroll
    for (int ti = 0; ti < 3; ++ti) {
        int tile = wv + ti * 16;
        bool tok = tile < ntiles;
#pragma unroll
        for (int rt = 0; rt < 2; ++rt) {
            int row = tile * 32 + rt * 16 + m16;
            float zx[16], zy[16];
#pragma unroll
            for (int j = 0; j < 16; ++j) { zx[j] = 0.f; zy[j] = 0.f; }
            if (tok && row < P) {
                size_t gr = (size_t)gbase + row;
                int na = jb.ga[gr] - nb20;
                int nb = jb.gb[gr] - nb20;
                int nc = 0;
                const float* w1r; const float* w2r; float isw;
                if (nT == 3) {
                    nc = jb.gc[gr] - nb20;
                    float4 iv = ((const float4*)jb.iso)[gr];   // one-hot eye(4)[ec]
                    int ec = (int)(iv.y + 2.f * iv.z + 3.f * iv.w + 0.5f);
                    w1r = wcT + ec * 64; w2r = wcT + 256 + ec * 64; isw = 1.f;
                } else {
                    w1r = wcT; w2r = wcT + 256; isw = jb.iso[gr];
                }
#pragma unroll
                for (int kt = 0; kt < 2; ++kt) {
                    int c4 = kt * 8 + quad * 2;
                    hsacc(hsA, na, c4, zx + kt * 8, zy + kt * 8);
                    hsacc(hsB, nb, c4, zx + kt * 8, zy + kt * 8);
                    if (nT == 3) hsacc(hsC, nc, c4, zx + kt * 8, zy + kt * 8);
                    int f0 = kt * 32 + quad * 8;
                    float4 wa0 = *(const float4*)(w1r + f0);
                    float4 wa1 = *(const float4*)(w1r + f0 + 4);
                    float4 wb0 = *(const float4*)(w2r + f0);
                    float4 wb1 = *(const float4*)(w2r + f0 + 4);
                    zx[kt*8+0] = fmaf(isw, wa0.x, zx[kt*8+0]); zx[kt*8+1] = fmaf(isw, wa0.y, zx[kt*8+1]);
                    zx[kt*8+2] = fmaf(isw, wa0.z, zx[kt*8+2]); zx[kt*8+3] = fmaf(isw, wa0.w, zx[kt*8+3]);
                    zx[kt*8+4] = fmaf(isw, wa1.x, zx[kt*8+4]); zx[kt*8+5] = fmaf(isw, wa1.y, zx[kt*8+5]);
                    zx[kt*8+6] = fmaf(isw, wa1.z, zx[kt*8+6]); zx[kt*8+7] = fmaf(isw, wa1.w, zx[kt*8+7]);
                    zy[kt*8+0] = fmaf(isw, wb0.x, zy[kt*8+0]); zy[kt*8+1] = fmaf(isw, wb0.y, zy[kt*8+1]);
                    zy[kt*8+2] = fmaf(isw, wb0.z, zy[kt*8+2]); zy[kt*8+3] = fmaf(isw, wb0.w, zy[kt*8+3]);
                    zy[kt*8+4] = fmaf(isw, wb1.x, zy[kt*8+4]); zy[kt*8+5] = fmaf(isw, wb1.y, zy[kt*8+5]);
                    zy[kt*8+6] = fmaf(isw, wb1.z, zy[kt*8+6]); zy[kt*8+7] = fmaf(isw, wb1.w, zy[kt*8+7]);
                }
                *(bf8v*)(mLDS + msw(row, quad))     = pack8(zy);
                *(bf8v*)(mLDS + msw(row, quad + 4)) = pack8(zy + 8);
            }
            z8[ti][rt][0] = pack8(zx);
            z8[ti][rt][1] = pack8(zx + 8);
        }
    }
    __syncthreads();

    // ---- P2: stage layer-1 W frags (frag-major) + neighsum-1 (z8 += sum m0[nbr]; relu)
    for (int i = t; i < 8192; i += 1024) {
        int e = i & 7, mm = (i >> 3) & 15, qq = (i >> 7) & 3;
        int kk = (i >> 9) & 1, mat = (i >> 10) & 1, nn = i >> 11;
        const float* W = mat ? jb.Wl2 : jb.Wl1;
        wstage[i] = __float2bfloat16(W[(nn * 16 + mm) * HID + kk * 32 + qq * 8 + e]);
    }
#pragma unroll
    for (int ti = 0; ti < 3; ++ti) {
        int tile = wv + ti * 16;
        bool tok = tile < ntiles;
#pragma unroll
        for (int rt = 0; rt < 2; ++rt) {
            int row = tile * 32 + rt * 16 + m16;
            float acc[16];
#pragma unroll
            for (int j = 0; j < 16; ++j) acc[j] = 0.f;
            accu4(asu4(z8[ti][rt][0]), acc);
            accu4(asu4(z8[ti][rt][1]), acc + 8);
            if (tok && row < P) {
                size_t gr = (size_t)gbase + row;
                int s = jb.rs[gr], e2 = jb.rs[gr + 1];
                int k = s;
                for (; k + 4 <= e2; k += 4) {
                    int n0 = jb.csrc[k] - gbase,     n1 = jb.csrc[k + 1] - gbase;
                    int n2 = jb.csrc[k + 2] - gbase, n3 = jb.csrc[k + 3] - gbase;
                    naccum(mLDS, n0, quad, acc); naccum(mLDS, n1, quad, acc);
                    naccum(mLDS, n2, quad, acc); naccum(mLDS, n3, quad, acc);
                }
                for (; k < e2; ++k) naccum(mLDS, jb.csrc[k] - gbase, quad, acc);
            }
            z8[ti][rt][0] = pack8relu(acc);
            z8[ti][rt][1] = pack8relu(acc + 8);
        }
    }
    __syncthreads();

    // ---- P3: dual MFMA GEMM. A = z8 (regs). zc -> global, m1 -> LDS (swizzled).
#pragma unroll
    for (int ti = 0; ti < 3; ++ti) {
        int tile = wv + ti * 16;
        if (tile < ntiles) {
            int j0 = tile * 32;
#pragma unroll
            for (int n = 0; n < 4; ++n) {
                const bf8v b1k0 = *(const bf8v*)(wstage + ((((n*2+0)*2+0)*4+quad)*16+m16)*8);
                const bf8v b1k1 = *(const bf8v*)(wstage + ((((n*2+0)*2+1)*4+quad)*16+m16)*8);
                const bf8v b2k0 = *(const bf8v*)(wstage + ((((n*2+1)*2+0)*4+quad)*16+m16)*8);
                const bf8v b2k1 = *(const bf8v*)(wstage + ((((n*2+1)*2+1)*4+quad)*16+m16)*8);
#pragma unroll
                for (int rt = 0; rt < 2; ++rt) {
                    f4v acca = {0.f, 0.f, 0.f, 0.f};
                    f4v accb = {0.f, 0.f, 0.f, 0.f};
                    acca = __builtin_amdgcn_mfma_f32_16x16x32_bf16(z8[ti][rt][0], b1k0, acca, 0, 0, 0);
                    acca = __builtin_amdgcn_mfma_f32_16x16x32_bf16(z8[ti][rt][1], b1k1, acca, 0, 0, 0);
                    accb = __builtin_amdgcn_mfma_f32_16x16x32_bf16(z8[ti][rt][0], b2k0, accb, 0, 0, 0);
                    accb = __builtin_amdgcn_mfma_f32_16x16x32_bf16(z8[ti][rt][1], b2k1, accb, 0, 0, 0);
                    int col = n * 16 + m16, ch = col >> 3, ce = col & 7;
#pragma unroll
                    for (int r = 0; r < 4; ++r) {
                        int row = j0 + rt * 16 + quad * 4 + r;
                        if (row < P) {
                            jb.zc[((size_t)gbase + row) * HID + col] = __float2bfloat16(acca[r]);
                            mLDS[(row << 6) + ((ch ^ (row & 7)) << 3) + ce] = __float2bfloat16(accb[r]);
                        }
                    }
                }
            }
        }
    }
    __syncthreads();

    // ---- P4: neighsum-2 + relu + per-graph segment sum (all in regs/LDS)
    float ps[16];
#pragma unroll
    for (int j = 0; j < 16; ++j) ps[j] = 0.f;
#pragma unroll
    for (int ti = 0; ti < 3; ++ti) {
        int tile = wv + ti * 16;
        bool tok = tile < ntiles;
#pragma unroll
        for (int rt = 0; rt < 2; ++rt) {
            int row = tile * 32 + rt * 16 + m16;
            if (tok && row < P) {
                float acc[16];
#pragma unroll
                for (int j = 0; j < 16; ++j) acc[j] = 0.f;
                u4v zc0 = *(const u4v*)(jb.zc + ((size_t)gbase + row) * HID + quad * 8);
                u4v zc1 = *(const u4v*)(jb.zc + ((size_t)gbase + row) * HID + 32 + quad * 8);
                accu4(zc0, acc); accu4(zc1, acc + 8);
                size_t gr = (size_t)gbase + row;
                int s = jb.rs[gr], e2 = jb.rs[gr + 1];
                int k = s;
                for (; k + 4 <= e2; k += 4) {
                    int n0 = jb.csrc[k] - gbase,     n1 = jb.csrc[k + 1] - gbase;
                    int n2 = jb.csrc[k + 2] - gbase, n3 = jb.csrc[k + 3] - gbase;
                    naccum(mLDS, n0, quad, acc); naccum(mLDS, n1, quad, acc);
                    naccum(mLDS, n2, quad, acc); naccum(mLDS, n3, quad, acc);
                }
                for (; k < e2; ++k) naccum(mLDS, jb.csrc[k] - gbase, quad, acc);
#pragma unroll
                for (int j = 0; j < 16; ++j) ps[j] += fmaxf(acc[j], 0.f);
            }
        }
    }
#pragma unroll
    for (int j = 0; j < 16; ++j) {
        ps[j] += __shfl_xor(ps[j], 1, 64);
        ps[j] += __shfl_xor(ps[j], 2, 64);
        ps[j] += __shfl_xor(ps[j], 4, 64);
        ps[j] += __shfl_xor(ps[j], 8, 64);
    }
    float* part = (float*)wstage;    // [16 waves][64 feats]
    if (m16 == 0) {
#pragma unroll
        for (int kt = 0; kt < 2; ++kt)
#pragma unroll
            for (int e = 0; e < 8; ++e)
                part[wv * 64 + kt * 32 + quad * 8 + e] = ps[kt * 8 + e];
    }
    __syncthreads();
    if (t < 64) {
        float s = 0.f;
#pragma unroll
        for (int w = 0; w < 16; ++w) s += part[w * 64 + t];
        comb[g * 192 + jb.comboff + t] = s;
    }
}

// -------- classifier
__global__ void classifier_k(const float* __restrict__ comb,
                             const float* __restrict__ cW1, const float* __restrict__ cb1,
                             const float* __restrict__ cW2, const float* __restrict__ cb2,
                             float* __restrict__ out) {
    __shared__ float row[192];
    __shared__ float hid[64];
    int g = blockIdx.x, t = threadIdx.x;
    for (int i = t; i < 192; i += 64) row[i] = comb[g * 192 + i];
    __syncthreads();
    float acc = cb1[t];
#pragma unroll 8
    for (int k = 0; k < 192; ++k) acc += row[k] * cW1[t * 192 + k];
    hid[t] = fmaxf(acc, 0.f);
    __syncthreads();
    if (t < 10) {
        float o = cb2[t];
#pragma unroll
        for (int k = 0; k < 64; ++k) o += hid[k] * cW2[t * 64 + k];
        out[g * 10 + t] = o;
    }
}

static inline int cdiv(long long a, long long b) { return (int)((a + b - 1) / b); }

extern "C" void kernel_launch(void* const* d_in, const int* in_sizes, int n_in,
                              void* d_out, int out_size, void* d_ws, size_t ws_size,
                              hipStream_t stream) {
    const float* x        = (const float*)d_in[0];
    const int*   eidx     = (const int*)d_in[1];
    const int*   gu2      = (const int*)d_in[3];
    const int*   gv2      = (const int*)d_in[4];
    const float* iso2     = (const float*)d_in[5];
    const int*   tedges   = (const int*)d_in[6];
    const int*   ga3      = (const int*)d_in[8];
    const int*   gb3      = (const int*)d_in[9];
    const int*   gc3      = (const int*)d_in[10];
    const float* iso3     = (const float*)d_in[11];
    const int*   hedges   = (const int*)d_in[12];
    const float* g1W1[3]  = {(const float*)d_in[14], (const float*)d_in[16], (const float*)d_in[18]};
    const float* g1W2[3]  = {(const float*)d_in[15], (const float*)d_in[17], (const float*)d_in[19]};
    const float* g2W1_0   = (const float*)d_in[20];
    const float* g2W2_0   = (const float*)d_in[21];
    const float* g2W1_1   = (const float*)d_in[22];
    const float* g2W2_1   = (const float*)d_in[23];
    const float* g3W1_0   = (const float*)d_in[24];
    const float* g3W2_0   = (const float*)d_in[25];
    const float* g3W1_1   = (const float*)d_in[26];
    const float* g3W2_1   = (const float*)d_in[27];
    const float* cW1      = (const float*)d_in[28];
    const float* cb1      = (const float*)d_in[29];
    const float* cW2      = (const float*)d_in[30];
    const float* cb2      = (const float*)d_in[31];
    float* out = (float*)d_out;

    const int N  = in_sizes[0] / 32;       // 2560
    const int E1 = in_sizes[1] / 2;
    const int n2 = in_sizes[3];            // 24320
    const int E2 = in_sizes[6] / 2;
    const int n3 = in_sizes[8];            // 145920
    const int E3 = in_sizes[12] / 2;
    const int G  = out_size / 10;          // 128
    const int per1 = N / G, per2 = n2 / G, per3 = n3 / G;

    // ---- workspace carve-up
    float* ws = (float*)d_ws;
    size_t off = 0;
    auto alloc = [&](size_t n) { off = (off + 3) & ~(size_t)3; float* p = ws + off; off += n; return p; };
    const size_t NH = (size_t)N * HID;
    float* h0 = alloc(NH);
    bf162* hUi = (bf162*)alloc(NH); bf162* hVi = (bf162*)alloc(NH);
    bf162* hAi = (bf162*)alloc(NH); bf162* hBi = (bf162*)alloc(NH); bf162* hCi = (bf162*)alloc(NH);
    bf16* z2c = (bf16*)alloc((size_t)n2 * HID / 2 + 64);
    bf16* z3c = (bf16*)alloc((size_t)n3 * HID / 2 + 64);
    float* comb = alloc((size_t)G * 192);
    int* iws = (int*)(ws + off);
    size_t ioff = 0;
    auto ialloc = [&](size_t n) { int* p = iws + ioff; ioff += n; return p; };
    int* rs1 = ialloc(N + 1);  int* cur1 = ialloc(N);  int* csrc1 = ialloc(E1);
    int* rs2 = ialloc(n2 + 1); int* cur2 = ialloc(n2); int* csrc2 = ialloc(E2);
    int* rs3 = ialloc(n3 + 1); int* cur3 = ialloc(n3); int* csrc3 = ialloc(E3);
    int* bsum1 = ialloc(256); int* bsum2 = ialloc(256); int* bsum3 = ialloc(256);
    (void)ws_size;

    dim3 B256(256);

    // ---- batched CSR build (6 dispatches; cur re-zero folded into scan3z)
    int nz1 = cdiv(N, 256), nz2 = cdiv(n2, 256), nz3 = cdiv(n3, 256);
    zero4_k<<<nz1 + nz2 + nz3, B256, 0, stream>>>(
        cur1, N, cur2, n2, cur3, n3, cur3, 0, nz1, nz2, nz3);
    int ne1 = cdiv(E1, 256), ne2 = cdiv(E2, 256), ne3 = cdiv(E3, 256);
    hist3_k<<<ne1 + ne2 + ne3, B256, 0, stream>>>(
        eidx, E1, cur1, tedges, E2, cur2, hedges, E3, cur3, ne1, ne2);
    int ns1 = cdiv(N + 1, 1024), ns2 = cdiv(n2 + 1, 1024), ns3 = cdiv(n3 + 1, 1024);
    scan1_3k<<<ns1 + ns2 + ns3, B256, 0, stream>>>(
        cur1, rs1, bsum1, N + 1, N, cur2, rs2, bsum2, n2 + 1, n2,
        cur3, rs3, bsum3, n3 + 1, n3, ns1, ns2);
    scan2_3k<<<1, B256, 0, stream>>>(bsum1, ns1, bsum2, ns2, bsum3, ns3);
    int nc1 = cdiv(N + 1, 256), nc2 = cdiv(n2 + 1, 256), nc3 = cdiv(n3 + 1, 256);
    scan3z_k<<<nc1 + nc2 + nc3 + nz1 + nz2 + nz3, B256, 0, stream>>>(
        rs1, bsum1, N + 1, rs2, bsum2, n2 + 1, rs3, bsum3, n3 + 1, nc1, nc2, nc3,
        cur1, N, cur2, n2, cur3, n3, nz1, nz2);
    fill3_k<<<ne1 + ne2 + ne3, B256, 0, stream>>>(
        eidx, E1, rs1, cur1, csrc1, tedges, E2, rs2, cur2, csrc2,
        hedges, E3, rs3, cur3, csrc3, ne1, ne2);

    // ================= level 1: FUSED single kernel (+ its segment sum) =================
    level1_k<<<G, B256, 0, stream>>>(x, rs1, csrc1,
        g1W1[0], g1W2[0], g1W1[1], g1W2[1], g1W1[2], g1W2[2], h0, comb, per1);
    const float* h = h0;

    // ---- all 5 table GEMMs in ONE dispatch
    {
        TJobs5 jobs;
        jobs.j[0] = {g2W1_0, g2W2_0, hUi, 129, 0};
        jobs.j[1] = {g2W1_0, g2W2_0, hVi, 129, 64};
        jobs.j[2] = {g3W1_0, g3W2_0, hAi, 196, 0};
        jobs.j[3] = {g3W1_0, g3W2_0, hBi, 196, 64};
        jobs.j[4] = {g3W1_0, g3W2_0, hCi, 196, 128};
        int bpj = cdiv(cdiv(N, RPW), 4);
        gemm2_table<<<bpj * 5, B256, 0, stream>>>(h, jobs, N, bpj);
    }

    // ================= levels 2+3: single fused per-graph kernel =================
    {
        FJob j3, j2;
        j3.tA = hAi; j3.tB = hBi; j3.tC = hCi;
        j3.ga = ga3; j3.gb = gb3; j3.gc = gc3;
        j3.iso = iso3; j3.wc1 = g3W1_0 + 192; j3.wc2 = g3W2_0 + 192; j3.ldw = 196; j3.isoC = 4;
        j3.Wl1 = g3W1_1; j3.Wl2 = g3W2_1; j3.rs = rs3; j3.csrc = csrc3;
        j3.zc = z3c; j3.P = per3; j3.comboff = 128;
        j2.tA = hUi; j2.tB = hVi; j2.tC = nullptr;
        j2.ga = gu2; j2.gb = gv2; j2.gc = nullptr;
        j2.iso = iso2; j2.wc1 = g2W1_0 + 128; j2.wc2 = g2W2_0 + 128; j2.ldw = 129; j2.isoC = 1;
        j2.Wl1 = g2W1_1; j2.Wl2 = g2W2_1; j2.rs = rs2; j2.csrc = csrc2;
        j2.zc = z2c; j2.P = per2; j2.comboff = 64;
        fused23_k<<<2 * G, 1024, 0, stream>>>(j3, j2, comb, G);
    }

    // ================= classifier =================
    classifier_k<<<G, 64, 0, stream>>>(comb, cW1, cb1, cW2, cb2, out);
}

// Round 4
// 307.061 us; speedup vs baseline: 1.4179x; 1.0648x over previous
//
#include <hip/hip_runtime.h>
#include <hip/hip_bf16.h>

#define HID 64
#define MROWS 1140   // C(20,3) rows per graph at level 3
#define PAD1 20      // level-1 in-degree <= 19
#define PAD2 40      // level-2 in-degree <= 38 (2 shared-elem choices x <=19 partners)
#define PAD3 60      // level-3 in-degree <= 54 (3 shared-pair choices x <=18 third-elems)

typedef __hip_bfloat16  bf16;
typedef __hip_bfloat162 bf162;
typedef unsigned short  u16;
typedef __attribute__((ext_vector_type(8))) short bf8v;
typedef __attribute__((ext_vector_type(4))) float f4v;
typedef __attribute__((ext_vector_type(4))) unsigned int u4v;
__device__ __forceinline__ float bl(bf16 h) { return __bfloat162float(h); }

// ======== padded CSR build: zero + fill (no hist/scan needed) ========
// csrc stores GRAPH-LOCAL ids as u16 (max row/graph = 1140 < 65536) -> 2x smaller,
// and removes the "- gbase" in every neighsum step.
__global__ void zero_k(int* p, int n) {
    int i = blockIdx.x * 256 + threadIdx.x;
    if (i < n) p[i] = 0;
}

__global__ void fillp_k(const int* e1, int E1, int* c1, u16* s1, int p1, int P1_,
                        const int* e2, int E2, int* c2, u16* s2, int p2, int P2_,
                        const int* e3, int E3, int* c3, u16* s3, int p3, int P3_,
                        int nb1, int nb2) {
    int b = blockIdx.x;
    const int* edges; int E; int* cur; u16* csrc; int pad; int P; int lb;
    if (b < nb1)            { edges = e1; E = E1; cur = c1; csrc = s1; pad = p1; P = P1_; lb = b; }
    else if (b < nb1 + nb2) { edges = e2; E = E2; cur = c2; csrc = s2; pad = p2; P = P2_; lb = b - nb1; }
    else                    { edges = e3; E = E3; cur = c3; csrc = s3; pad = p3; P = P3_; lb = b - nb1 - nb2; }
    int e = lb * 256 + threadIdx.x;
    if (e >= E) return;
    int d = edges[E + e];
    int slot = atomicAdd(&cur[d], 1);
    if (slot < pad) csrc[(size_t)d * pad + slot] = (u16)(edges[e] % P);   // local id
}

// ======== level-1 GNN + segsum + the 5 table projections (h stays in LDS) ========
struct TJob { const float* Wa; const float* Wb; bf162* o; int ldw; int coloff; };
struct TJobs5 { TJob j[5]; };

__global__ __launch_bounds__(256)
void level1T_k(const float* __restrict__ x,
               const int* __restrict__ cnt1, const u16* __restrict__ csrc1,
               const float* __restrict__ W10, const float* __restrict__ W20,
               const float* __restrict__ W11, const float* __restrict__ W21,
               const float* __restrict__ W12, const float* __restrict__ W22,
               TJobs5 jobs, float* __restrict__ comb, int nper) {
    __shared__ float hbuf[20][64];
    __shared__ float mbuf[20][64];
    __shared__ float wl1[64 * 64];
    __shared__ float wl2[64 * 64];
    int g = blockIdx.x, t = threadIdx.x;
    int wv = t >> 6, lane = t & 63;
    int base = g * nper;
    for (int i = t; i < 20 * 32; i += 256)
        hbuf[i >> 5][i & 31] = x[(size_t)(base + (i >> 5)) * 32 + (i & 31)];
    const float* W1s[3] = {W10, W11, W12};
    const float* W2s[3] = {W20, W21, W22};
#pragma unroll 1
    for (int l = 0; l < 3; ++l) {
        int K = (l == 0) ? 32 : 64;
        const float* W1 = W1s[l];
        const float* W2 = W2s[l];
        __syncthreads();
        for (int i = t; i < K * 64; i += 256) {
            int k = i >> 6, col = i & 63;
            wl1[i] = W1[col * K + k];
            wl2[i] = W2[col * K + k];
        }
        __syncthreads();
        float accz[5], accm[5];
#pragma unroll
        for (int ri = 0; ri < 5; ++ri) {
            int r = wv + ri * 4;
            float az = 0.f, am = 0.f;
            for (int k = 0; k < K; ++k) {
                float hv = hbuf[r][k];
                az = fmaf(hv, wl1[k * 64 + lane], az);
                am = fmaf(hv, wl2[k * 64 + lane], am);
            }
            accz[ri] = az; accm[ri] = am;
        }
        __syncthreads();
#pragma unroll
        for (int ri = 0; ri < 5; ++ri)
            mbuf[wv + ri * 4][lane] = accm[ri];
        __syncthreads();
#pragma unroll
        for (int ri = 0; ri < 5; ++ri) {
            int r = wv + ri * 4;
            float acc = accz[ri];
            int cnt = cnt1[base + r];
            const u16* cs = csrc1 + (size_t)(base + r) * PAD1;
            for (int k = 0; k < cnt; ++k)
                acc += mbuf[cs[k]][lane];
            hbuf[r][lane] = fmaxf(acc, 0.f);
        }
    }
    __syncthreads();
    if (t < 64) {
        float s = 0.f;
        for (int r = 0; r < nper; ++r) s += hbuf[r][t];
        comb[g * 192 + t] = s;   // level-1 embedding, cols 0..63
    }
    // ---- 5 table projections (bf162 interleaved outputs)
#pragma unroll 1
    for (int jj = 0; jj < 5; ++jj) {
        const float* Wa = jobs.j[jj].Wa;
        const float* Wb = jobs.j[jj].Wb;
        bf162* o = jobs.j[jj].o;
        int ldw = jobs.j[jj].ldw, coloff = jobs.j[jj].coloff;
        __syncthreads();
        for (int i = t; i < 4096; i += 256) {
            int k = i >> 6, col = i & 63;
            wl1[i] = Wa[col * ldw + coloff + k];
            wl2[i] = Wb[col * ldw + coloff + k];
        }
        __syncthreads();
#pragma unroll
        for (int p = 0; p < 5; ++p) {
            int idx = t + p * 256;
            int node = idx >> 6, ff = idx & 63;
            float sx = 0.f, sy = 0.f;
            for (int k = 0; k < 64; ++k) {
                float hv = hbuf[node][k];
                sx = fmaf(hv, wl1[k * 64 + ff], sx);
                sy = fmaf(hv, wl2[k * 64 + ff], sy);
            }
            bf162 v; v.x = __float2bfloat16(sx); v.y = __float2bfloat16(sy);
            o[(size_t)(g * 20 + node) * 64 + ff] = v;
        }
    }
}

// ======== FUSED levels 2+3, split across (graph, half) with rt-granular ownership ====
// Block (g,h) owns rows with rt==h (16-row MFMA-fragment granularity -> perfect wave
// balance; all 256 blocks do equal work). K1: gather (m0 full in LDS; z owned in regs)
// + neighsum-1 (owned) + dual MFMA (owned) -> zc, m1 to GLOBAL. K2: stage m1 (full
// graph) -> LDS, neighsum-2 + segsum for owned rows, atomicAdd into comb.
struct FJob {
    const bf162 *tA, *tB, *tC;      // projected node tables (tC null => level 2)
    const int *ga, *gb, *gc;        // global node ids per row
    const float *iso;               // level3: float4 one-hot; level2: float
    const float *wc1, *wc2; int ldw, isoC;
    const float *Wl1, *Wl2;         // layer-1 weights [64][64]
    const u16 *csrc; const int *cnt; int pad;   // padded CSR (local ids)
    bf16 *zc; bf16 *m1g;            // layer-1 preact + message scratch (bf16 [n][64])
    int P, ntiles, comboff;
};

__device__ __forceinline__ int msw(int row, int ch) {
    return (row << 6) + ((ch ^ (row & 7)) << 3);
}
__device__ __forceinline__ void accu4(u4v v, float* f) {
#pragma unroll
    for (int i = 0; i < 4; ++i) {
        f[2 * i]     += __uint_as_float(v[i] << 16);
        f[2 * i + 1] += __uint_as_float(v[i] & 0xffff0000u);
    }
}
__device__ __forceinline__ void accxy4(u4v v, float* zx, float* zy) {
#pragma unroll
    for (int i = 0; i < 4; ++i) {
        zx[i] += __uint_as_float(v[i] << 16);
        zy[i] += __uint_as_float(v[i] & 0xffff0000u);
    }
}
__device__ __forceinline__ bf8v pack8(const float* f) {
    bf16 tmp[8];
#pragma unroll
    for (int e = 0; e < 8; ++e) tmp[e] = __float2bfloat16(f[e]);
    bf8v r; __builtin_memcpy(&r, tmp, 16); return r;
}
__device__ __forceinline__ bf8v pack8relu(const float* f) {
    bf16 tmp[8];
#pragma unroll
    for (int e = 0; e < 8; ++e) tmp[e] = __float2bfloat16(fmaxf(f[e], 0.f));
    bf8v r; __builtin_memcpy(&r, tmp, 16); return r;
}
__device__ __forceinline__ u4v asu4(bf8v v) { u4v r; __builtin_memcpy(&r, &v, 16); return r; }
__device__ __forceinline__ void hsacc(const bf162* tb, int nd, int c4, float* zx, float* zy) {
    u4v v0 = *(const u4v*)(tb + (nd << 6) + (((c4    ) ^ (nd & 15)) << 2));
    u4v v1 = *(const u4v*)(tb + (nd << 6) + (((c4 + 1) ^ (nd & 15)) << 2));
    accxy4(v0, zx, zy);
    accxy4(v1, zx + 4, zy + 4);
}
__device__ __forceinline__ void hsaccY(const bf162* tb, int nd, int c4, float* zy) {
    u4v v0 = *(const u4v*)(tb + (nd << 6) + (((c4    ) ^ (nd & 15)) << 2));
    u4v v1 = *(const u4v*)(tb + (nd << 6) + (((c4 + 1) ^ (nd & 15)) << 2));
#pragma unroll
    for (int i = 0; i < 4; ++i) {
        zy[i]     += __uint_as_float(v0[i] & 0xffff0000u);
        zy[4 + i] += __uint_as_float(v1[i] & 0xffff0000u);
    }
}
__device__ __forceinline__ void naccum(const bf16* mL, int nbr, int quad, float* acc) {
    u4v v0 = *(const u4v*)(mL + msw(nbr, quad));
    u4v v1 = *(const u4v*)(mL + msw(nbr, quad + 4));
    accu4(v0, acc); accu4(v1, acc + 8);
}

__device__ __forceinline__ void run_k1(const FJob& jb, int g, int h,
                                       bf16* mLDS, bf16* wstage) {
    int t = threadIdx.x;
    const int P = jb.P, nT = jb.tC ? 3 : 2;
    const int gbase = g * P, nb20 = g * 20;
    int lane = t & 63, wv = t >> 6, quad = lane >> 4, m16 = lane & 15;

    // ---- P0: stage projected node tables (swizzled) + iso-weight table
    bf162* hsA = (bf162*)wstage;
    const bf162* hsB = hsA + 1280;
    const bf162* hsC = hsA + 2560;
    for (int i = t; i < nT * 1280; i += 1024) {
        int table = i / 1280, rem = i - table * 1280;
        int node = rem >> 6, f = rem & 63, c4 = f >> 2;
        const bf162* src = (table == 0) ? jb.tA : (table == 1) ? jb.tB : jb.tC;
        hsA[table * 1280 + (node << 6) + ((c4 ^ (node & 15)) << 2) + (f & 3)] =
            src[(size_t)g * 1280 + rem];
    }
    float* wcT = (float*)(wstage + 7680);   // [2 mats][4 c][64 f]
    if (t < 512) {
        int mat = t >> 8, c = (t >> 6) & 3, f = t & 63;
        const float* W = mat ? jb.wc2 : jb.wc1;
        wcT[mat * 256 + c * 64 + f] = (c < jb.isoC) ? W[f * jb.ldw + c] : 0.f;
    }
    __syncthreads();

    // ---- P1: layer-0 gather -> z (regs, owned rt only) + m0 (LDS, all rows)
    bf8v z8[3][2];
#pragma unroll
    for (int k = 0; k < 3; ++k) {
        int tile = wv + k * 16;
        if (tile >= jb.ntiles) continue;
#pragma unroll
        for (int rt = 0; rt < 2; ++rt) {
            bool own = (rt == h);
            int row = tile * 32 + rt * 16 + m16;
            float zx[16], zy[16];
#pragma unroll
            for (int j = 0; j < 16; ++j) { zx[j] = 0.f; zy[j] = 0.f; }
            if (row < P) {
                size_t gr = (size_t)gbase + row;
                int na = jb.ga[gr] - nb20;
                int nb = jb.gb[gr] - nb20;
                int nc = 0;
                const float* w1r; const float* w2r; float isw;
                if (nT == 3) {
                    nc = jb.gc[gr] - nb20;
                    float4 iv = ((const float4*)jb.iso)[gr];   // one-hot eye(4)[ec]
                    int ec = (int)(iv.y + 2.f * iv.z + 3.f * iv.w + 0.5f);
                    w1r = wcT + ec * 64; w2r = wcT + 256 + ec * 64; isw = 1.f;
                } else {
                    w1r = wcT; w2r = wcT + 256; isw = jb.iso[gr];
                }
#pragma unroll
                for (int kt = 0; kt < 2; ++kt) {
                    int c4 = kt * 8 + quad * 2;
                    int f0 = kt * 32 + quad * 8;
                    if (own) {
                        hsacc(hsA, na, c4, zx + kt * 8, zy + kt * 8);
                        hsacc(hsB, nb, c4, zx + kt * 8, zy + kt * 8);
                        if (nT == 3) hsacc(hsC, nc, c4, zx + kt * 8, zy + kt * 8);
#pragma unroll
                        for (int e = 0; e < 8; ++e)
                            zx[kt * 8 + e] = fmaf(isw, w1r[f0 + e], zx[kt * 8 + e]);
                    } else {
                        hsaccY(hsA, na, c4, zy + kt * 8);
                        hsaccY(hsB, nb, c4, zy + kt * 8);
                        if (nT == 3) hsaccY(hsC, nc, c4, zy + kt * 8);
                    }
#pragma unroll
                    for (int e = 0; e < 8; ++e)
                        zy[kt * 8 + e] = fmaf(isw, w2r[f0 + e], zy[kt * 8 + e]);
                }
                *(bf8v*)(mLDS + msw(row, quad))     = pack8(zy);
                *(bf8v*)(mLDS + msw(row, quad + 4)) = pack8(zy + 8);
            }
            if (own) { z8[k][0] = pack8(zx); z8[k][1] = pack8(zx + 8); }
        }
    }
    __syncthreads();

    // ---- P2: stage layer-1 W frags (frag-major) + neighsum-1 for owned rows
    for (int i = t; i < 8192; i += 1024) {
        int e = i & 7, mm = (i >> 3) & 15, qq = (i >> 7) & 3;
        int kk = (i >> 9) & 1, mat = (i >> 10) & 1, nn = i >> 11;
        const float* W = mat ? jb.Wl2 : jb.Wl1;
        wstage[i] = __float2bfloat16(W[(nn * 16 + mm) * HID + kk * 32 + qq * 8 + e]);
    }
#pragma unroll
    for (int k = 0; k < 3; ++k) {
        int tile = wv + k * 16;
        if (tile >= jb.ntiles) continue;
        int row = tile * 32 + h * 16 + m16;
        float acc[16];
#pragma unroll
        for (int j = 0; j < 16; ++j) acc[j] = 0.f;
        accu4(asu4(z8[k][0]), acc);
        accu4(asu4(z8[k][1]), acc + 8);
        if (row < P) {
            size_t gr = (size_t)gbase + row;
            int cnt = jb.cnt[gr];
            const u16* cs = jb.csrc + gr * (size_t)jb.pad;
            int kk = 0;
            for (; kk + 4 <= cnt; kk += 4) {
                int n0 = cs[kk], n1 = cs[kk + 1], n2 = cs[kk + 2], n3 = cs[kk + 3];
                naccum(mLDS, n0, quad, acc); naccum(mLDS, n1, quad, acc);
                naccum(mLDS, n2, quad, acc); naccum(mLDS, n3, quad, acc);
            }
            for (; kk < cnt; ++kk) naccum(mLDS, cs[kk], quad, acc);
        }
        z8[k][0] = pack8relu(acc);
        z8[k][1] = pack8relu(acc + 8);
    }
    __syncthreads();

    // ---- P3: dual MFMA GEMM (owned rt only). zc + m1 -> GLOBAL.
#pragma unroll
    for (int k = 0; k < 3; ++k) {
        int tile = wv + k * 16;
        if (tile >= jb.ntiles) continue;
        int j0 = tile * 32;
#pragma unroll
        for (int n = 0; n < 4; ++n) {
            const bf8v b1k0 = *(const bf8v*)(wstage + ((((n*2+0)*2+0)*4+quad)*16+m16)*8);
            const bf8v b1k1 = *(const bf8v*)(wstage + ((((n*2+0)*2+1)*4+quad)*16+m16)*8);
            const bf8v b2k0 = *(const bf8v*)(wstage + ((((n*2+1)*2+0)*4+quad)*16+m16)*8);
            const bf8v b2k1 = *(const bf8v*)(wstage + ((((n*2+1)*2+1)*4+quad)*16+m16)*8);
            f4v acca = {0.f, 0.f, 0.f, 0.f};
            f4v accb = {0.f, 0.f, 0.f, 0.f};
            acca = __builtin_amdgcn_mfma_f32_16x16x32_bf16(z8[k][0], b1k0, acca, 0, 0, 0);
            acca = __builtin_amdgcn_mfma_f32_16x16x32_bf16(z8[k][1], b1k1, acca, 0, 0, 0);
            accb = __builtin_amdgcn_mfma_f32_16x16x32_bf16(z8[k][0], b2k0, accb, 0, 0, 0);
            accb = __builtin_amdgcn_mfma_f32_16x16x32_bf16(z8[k][1], b2k1, accb, 0, 0, 0);
            int col = n * 16 + m16;
#pragma unroll
            for (int r = 0; r < 4; ++r) {
                int row = j0 + h * 16 + quad * 4 + r;
                if (row < P) {
                    jb.zc[((size_t)gbase + row) * HID + col]  = __float2bfloat16(acca[r]);
                    jb.m1g[((size_t)gbase + row) * HID + col] = __float2bfloat16(accb[r]);
                }
            }
        }
    }
}

__global__ __launch_bounds__(1024, 1)
void fused23a_k(FJob j3, FJob j2, float* __restrict__ comb, int G) {
    __shared__ __align__(16) bf16 mLDS[MROWS * HID];   // 145920 B
    __shared__ __align__(16) bf16 wstage[8768];        //  17536 B
    int b = blockIdx.x;
    int g = b >> 1, h = b & 1;
    if (h == 0 && threadIdx.x < 128) comb[g * 192 + 64 + threadIdx.x] = 0.f;
    run_k1(j3, g, h, mLDS, wstage);
    __syncthreads();
    run_k1(j2, g, h, mLDS, wstage);
}

__device__ __forceinline__ void run_k2(const FJob& jb, int g, int h,
                                       bf16* mLDS, float* part, float* comb) {
    int t = threadIdx.x;
    const int P = jb.P;
    const int gbase = g * P;
    int lane = t & 63, wv = t >> 6, quad = lane >> 4, m16 = lane & 15;
    // stage m1 (full graph) global -> LDS, swizzled
    for (int i = t; i < P * 8; i += 1024) {
        int row = i >> 3, ch = i & 7;
        u4v v = *(const u4v*)(jb.m1g + ((size_t)gbase + row) * HID + ch * 8);
        *(u4v*)(mLDS + msw(row, ch)) = v;
    }
    __syncthreads();
    float ps[16];
#pragma unroll
    for (int j = 0; j < 16; ++j) ps[j] = 0.f;
#pragma unroll
    for (int k = 0; k < 3; ++k) {
        int tile = wv + k * 16;
        if (tile >= jb.ntiles) continue;
        int row = tile * 32 + h * 16 + m16;
        if (row < P) {
            float acc[16];
#pragma unroll
            for (int j = 0; j < 16; ++j) acc[j] = 0.f;
            size_t gr = (size_t)gbase + row;
            u4v zc0 = *(const u4v*)(jb.zc + gr * HID + quad * 8);
            u4v zc1 = *(const u4v*)(jb.zc + gr * HID + 32 + quad * 8);
            accu4(zc0, acc); accu4(zc1, acc + 8);
            int cnt = jb.cnt[gr];
            const u16* cs = jb.csrc + gr * (size_t)jb.pad;
            int kk = 0;
            for (; kk + 4 <= cnt; kk += 4) {
                int n0 = cs[kk], n1 = cs[kk + 1], n2 = cs[kk + 2], n3 = cs[kk + 3];
                naccum(mLDS, n0, quad, acc); naccum(mLDS, n1, quad, acc);
                naccum(mLDS, n2, quad, acc); naccum(mLDS, n3, quad, acc);
            }
            for (; kk < cnt; ++kk) naccum(mLDS, cs[kk], quad, acc);
#pragma unroll
            for (int j = 0; j < 16; ++j) ps[j] += fmaxf(acc[j], 0.f);
        }
    }
#pragma unroll
    for (int j = 0; j < 16; ++j) {
        ps[j] += __shfl_xor(ps[j], 1, 64);
        ps[j] += __shfl_xor(ps[j], 2, 64);
        ps[j] += __shfl_xor(ps[j], 4, 64);
        ps[j] += __shfl_xor(ps[j], 8, 64);
    }
    if (m16 == 0) {
#pragma unroll
        for (int kt = 0; kt < 2; ++kt)
#pragma unroll
            for (int e = 0; e < 8; ++e)
                part[wv * 64 + kt * 32 + quad * 8 + e] = ps[kt * 8 + e];
    }
    __syncthreads();
    if (t < 64) {
        float s = 0.f;
#pragma unroll
        for (int w = 0; w < 16; ++w) s += part[w * 64 + t];
        atomicAdd(&comb[g * 192 + jb.comboff + t], s);
    }
    __syncthreads();
}

__global__ __launch_bounds__(1024, 1)
void fused23b_k(FJob j3, FJob j2, float* __restrict__ comb, int G) {
    __shared__ __align__(16) bf16 mLDS[MROWS * HID];
    __shared__ float part[1024];
    int b = blockIdx.x;
    int g = b >> 1, h = b & 1;
    run_k2(j3, g, h, mLDS, part, comb);
    run_k2(j2, g, h, mLDS, part, comb);
}

// -------- classifier
__global__ void classifier_k(const float* __restrict__ comb,
                             const float* __restrict__ cW1, const float* __restrict__ cb1,
                             const float* __restrict__ cW2, const float* __restrict__ cb2,
                             float* __restrict__ out) {
    __shared__ float row[192];
    __shared__ float hid[64];
    int g = blockIdx.x, t = threadIdx.x;
    for (int i = t; i < 192; i += 64) row[i] = comb[g * 192 + i];
    __syncthreads();
    float acc = cb1[t];
#pragma unroll 8
    for (int k = 0; k < 192; ++k) acc += row[k] * cW1[t * 192 + k];
    hid[t] = fmaxf(acc, 0.f);
    __syncthreads();
    if (t < 10) {
        float o = cb2[t];
#pragma unroll
        for (int k = 0; k < 64; ++k) o += hid[k] * cW2[t * 64 + k];
        out[g * 10 + t] = o;
    }
}

static inline int cdiv(long long a, long long b) { return (int)((a + b - 1) / b); }

extern "C" void kernel_launch(void* const* d_in, const int* in_sizes, int n_in,
                              void* d_out, int out_size, void* d_ws, size_t ws_size,
                              hipStream_t stream) {
    const float* x        = (const float*)d_in[0];
    const int*   eidx     = (const int*)d_in[1];
    const int*   gu2      = (const int*)d_in[3];
    const int*   gv2      = (const int*)d_in[4];
    const float* iso2     = (const float*)d_in[5];
    const int*   tedges   = (const int*)d_in[6];
    const int*   ga3      = (const int*)d_in[8];
    const int*   gb3      = (const int*)d_in[9];
    const int*   gc3      = (const int*)d_in[10];
    const float* iso3     = (const float*)d_in[11];
    const int*   hedges   = (const int*)d_in[12];
    const float* g1W1[3]  = {(const float*)d_in[14], (const float*)d_in[16], (const float*)d_in[18]};
    const float* g1W2[3]  = {(const float*)d_in[15], (const float*)d_in[17], (const float*)d_in[19]};
    const float* g2W1_0   = (const float*)d_in[20];
    const float* g2W2_0   = (const float*)d_in[21];
    const float* g2W1_1   = (const float*)d_in[22];
    const float* g2W2_1   = (const float*)d_in[23];
    const float* g3W1_0   = (const float*)d_in[24];
    const float* g3W2_0   = (const float*)d_in[25];
    const float* g3W1_1   = (const float*)d_in[26];
    const float* g3W2_1   = (const float*)d_in[27];
    const float* cW1      = (const float*)d_in[28];
    const float* cb1      = (const float*)d_in[29];
    const float* cW2      = (const float*)d_in[30];
    const float* cb2      = (const float*)d_in[31];
    float* out = (float*)d_out;

    const int N  = in_sizes[0] / 32;       // 2560
    const int E1 = in_sizes[1] / 2;
    const int n2 = in_sizes[3];            // 24320
    const int E2 = in_sizes[6] / 2;
    const int n3 = in_sizes[8];            // 145920
    const int E3 = in_sizes[12] / 2;
    const int G  = out_size / 10;          // 128
    const int per1 = N / G, per2 = n2 / G, per3 = n3 / G;

    // ---- workspace carve-up (~67 MB total; round-0's passing layout used ~77 MB)
    float* ws = (float*)d_ws;
    size_t off = 0;
    auto alloc = [&](size_t n) { off = (off + 3) & ~(size_t)3; float* p = ws + off; off += n; return p; };
    const size_t NH = (size_t)N * HID;
    bf162* hUi = (bf162*)alloc(NH); bf162* hVi = (bf162*)alloc(NH);
    bf162* hAi = (bf162*)alloc(NH); bf162* hBi = (bf162*)alloc(NH); bf162* hCi = (bf162*)alloc(NH);
    bf16* z2c = (bf16*)alloc((size_t)n2 * HID / 2 + 64);
    bf16* z3c = (bf16*)alloc((size_t)n3 * HID / 2 + 64);
    bf16* m2g = (bf16*)alloc((size_t)n2 * HID / 2 + 64);
    bf16* m3g = (bf16*)alloc((size_t)n3 * HID / 2 + 64);
    float* comb = alloc((size_t)G * 192);
    int* iws = (int*)(ws + off);
    size_t ioff = 0;
    auto ialloc = [&](size_t n) { int* p = iws + ioff; ioff += n; return p; };
    int* cur1 = ialloc(N); int* cur2 = ialloc(n2); int* cur3 = ialloc(n3);   // contiguous
    u16* u16ws = (u16*)(iws + ioff);
    size_t uoff = 0;
    auto ualloc = [&](size_t n) { u16* p = u16ws + uoff; uoff += n; return p; };
    u16* csrc1 = ualloc((size_t)N * PAD1);
    u16* csrc2 = ualloc((size_t)n2 * PAD2);
    u16* csrc3 = ualloc((size_t)n3 * PAD3);
    (void)ws_size;

    dim3 B256(256);

    // ---- padded CSR build: zero + fill (2 dispatches)
    int ncnt = N + n2 + n3;
    zero_k<<<cdiv(ncnt, 256), B256, 0, stream>>>(cur1, ncnt);
    int ne1 = cdiv(E1, 256), ne2 = cdiv(E2, 256), ne3 = cdiv(E3, 256);
    fillp_k<<<ne1 + ne2 + ne3, B256, 0, stream>>>(
        eidx, E1, cur1, csrc1, PAD1, per1,
        tedges, E2, cur2, csrc2, PAD2, per2,
        hedges, E3, cur3, csrc3, PAD3, per3, ne1, ne2);

    // ---- level 1 GNN + segsum + 5 table projections (1 dispatch)
    {
        TJobs5 jobs;
        jobs.j[0] = {g2W1_0, g2W2_0, hUi, 129, 0};
        jobs.j[1] = {g2W1_0, g2W2_0, hVi, 129, 64};
        jobs.j[2] = {g3W1_0, g3W2_0, hAi, 196, 0};
        jobs.j[3] = {g3W1_0, g3W2_0, hBi, 196, 64};
        jobs.j[4] = {g3W1_0, g3W2_0, hCi, 196, 128};
        level1T_k<<<G, B256, 0, stream>>>(x, cur1, csrc1,
            g1W1[0], g1W2[0], g1W1[1], g1W2[1], g1W1[2], g1W2[2], jobs, comb, per1);
    }

    // ---- levels 2+3: split K1/K2, (graph, half) blocks
    {
        FJob j3, j2;
        j3.tA = hAi; j3.tB = hBi; j3.tC = hCi;
        j3.ga = ga3; j3.gb = gb3; j3.gc = gc3;
        j3.iso = iso3; j3.wc1 = g3W1_0 + 192; j3.wc2 = g3W2_0 + 192; j3.ldw = 196; j3.isoC = 4;
        j3.Wl1 = g3W1_1; j3.Wl2 = g3W2_1;
        j3.csrc = csrc3; j3.cnt = cur3; j3.pad = PAD3;
        j3.zc = z3c; j3.m1g = m3g;
        j3.P = per3; j3.ntiles = (per3 + 31) >> 5; j3.comboff = 128;

        j2.tA = hUi; j2.tB = hVi; j2.tC = nullptr;
        j2.ga = gu2; j2.gb = gv2; j2.gc = nullptr;
        j2.iso = iso2; j2.wc1 = g2W1_0 + 128; j2.wc2 = g2W2_0 + 128; j2.ldw = 129; j2.isoC = 1;
        j2.Wl1 = g2W1_1; j2.Wl2 = g2W2_1;
        j2.csrc = csrc2; j2.cnt = cur2; j2.pad = PAD2;
        j2.zc = z2c; j2.m1g = m2g;
        j2.P = per2; j2.ntiles = (per2 + 31) >> 5; j2.comboff = 64;

        fused23a_k<<<2 * G, 1024, 0, stream>>>(j3, j2, comb, G);
        fused23b_k<<<2 * G, 1024, 0, stream>>>(j3, j2, comb, G);
    }

    // ---- classifier
    classifier_k<<<G, 64, 0, stream>>>(comb, cW1, cb1, cW2, cb2, out);
}